// Round 2
// baseline (501.858 us; speedup 1.0000x reference)
//
#include <hip/hip_runtime.h>
#include <hip/hip_bf16.h>
#include <stdint.h>

// GNNStream: enc GEMM -> LN/ReLU -> QKV GEMMs -> scores=q k^T -> softmax*adj*mask
// -> attn v -> bn GEMM -> LN/ReLU + masked pool -> MLP head.
// All big GEMMs: bf16 MFMA 16x16x32, 128x128 tile, BK=32, global_load_lds(16B).
// mask is int32 on device (harness: integer -> const int*).

typedef __hip_bfloat16 bf16_t;
typedef __attribute__((ext_vector_type(8))) short bf16x8;
typedef __attribute__((ext_vector_type(4))) float f32x4;

__device__ __forceinline__ void cp16_to_lds(const void* g, void* lds) {
  __builtin_amdgcn_global_load_lds(
      (__attribute__((address_space(1))) void*)(g),
      (__attribute__((address_space(3))) void*)(lds), 16, 0, 0);
}

// C = A * B^T (+bias) * scale.  A: M x K row-major, B: N x K row-major, bf16.
// mode 0: write bf16 natural (ldC). mode 1: write v^T layout [b][n][t] (qkv-v).
// mode 2: write f32 natural.
__global__ __launch_bounds__(256) void gemm_bt(
    const bf16_t* __restrict__ A, const bf16_t* __restrict__ B,
    void* __restrict__ Cv, const float* __restrict__ bias, float scale, int K,
    long sA, long sB, long sC, int ldC, int mode)
{
  __shared__ __align__(16) bf16_t lA[128 * 32];
  __shared__ __align__(16) bf16_t lB[128 * 32];
  const int z = blockIdx.z;
  A += (long)z * sA;
  B += (long)z * sB;
  const int m0 = blockIdx.y * 128, n0 = blockIdx.x * 128;
  const int tid = threadIdx.x;
  const int w = tid >> 6, lane = tid & 63;
  const int wm = w >> 1, wn = w & 1;

  const int rr = tid >> 2;         // row 0..63 within chunk
  const int cc = (tid & 3) * 8;    // k-offset 0/8/16/24
  const bf16_t* a0 = A + (long)(m0 + rr) * K + cc;
  const bf16_t* b0 = B + (long)(n0 + rr) * K + cc;
  const long rowskip = (long)64 * K;

  char* lAc = (char*)lA;
  char* lBc = (char*)lB;
  const int ofs0 = w * 1024;          // wave-uniform LDS chunk base (bytes)
  const int ofs1 = 4096 + w * 1024;

  f32x4 acc[4][4] = {};
  const int nkt = K >> 5;
  for (int kt = 0; kt < nkt; ++kt) {
    __syncthreads();
    cp16_to_lds(a0, lAc + ofs0);
    cp16_to_lds(a0 + rowskip, lAc + ofs1);
    cp16_to_lds(b0, lBc + ofs0);
    cp16_to_lds(b0 + rowskip, lBc + ofs1);
    a0 += 32; b0 += 32;
    __syncthreads();

    const int kb = (lane >> 4) * 8;
    const int rsel = lane & 15;
    bf16x8 af[4], bfr[4];
#pragma unroll
    for (int i = 0; i < 4; ++i) {
      af[i]  = *(const bf16x8*)&lA[(wm * 64 + i * 16 + rsel) * 32 + kb];
      bfr[i] = *(const bf16x8*)&lB[(wn * 64 + i * 16 + rsel) * 32 + kb];
    }
#pragma unroll
    for (int i = 0; i < 4; ++i)
#pragma unroll
      for (int j = 0; j < 4; ++j)
        acc[i][j] = __builtin_amdgcn_mfma_f32_16x16x32_bf16(af[i], bfr[j], acc[i][j], 0, 0, 0);
  }

  const int col = lane & 15, quad = lane >> 4;
#pragma unroll
  for (int j = 0; j < 4; ++j) {
    const int ng = n0 + wn * 64 + j * 16 + col;
    const float bv = bias ? bias[ng] : 0.0f;
#pragma unroll
    for (int i = 0; i < 4; ++i) {
      const int mg = m0 + wm * 64 + i * 16 + quad * 4;
#pragma unroll
      for (int r = 0; r < 4; ++r) {
        const float v = acc[i][j][r] * scale + bv;
        const long mrow = mg + r;
        if (mode == 0) {
          ((bf16_t*)Cv)[(long)z * sC + mrow * ldC + ng] = __float2bfloat16(v);
        } else if (mode == 2) {
          ((float*)Cv)[(long)z * sC + mrow * ldC + ng] = v;
        } else { // v^T: [b][d=ng][t], b = mrow/2048
          const long bb = mrow >> 11, t = mrow & 2047;
          ((bf16_t*)Cv)[(bb * 512 + ng) * 2048 + t] = __float2bfloat16(v);
        }
      }
    }
  }
}

__global__ __launch_bounds__(256) void cast_bf16_k(
    const float* __restrict__ in, bf16_t* __restrict__ o, int n) {
  const int i = blockIdx.x * 256 + threadIdx.x;
  if (i < n) o[i] = __float2bfloat16(in[i]);
}

// in: K x N f32 -> out: N x K bf16
__global__ __launch_bounds__(256) void transpose_cast_k(
    const float* __restrict__ in, bf16_t* __restrict__ o, int K, int N) {
  const int i = blockIdx.x * 256 + threadIdx.x;
  if (i < K * N) {
    const int k = i / N, n = i - k * N;
    o[n * K + k] = __float2bfloat16(in[i]);
  }
}

// in-place LayerNorm(512) + ReLU on bf16 rows
__global__ __launch_bounds__(256) void ln_relu_h(
    bf16_t* __restrict__ X, const float* __restrict__ g, const float* __restrict__ b)
{
  const int tid = threadIdx.x;
  const long base = (long)blockIdx.x * 512;
  const float x0 = __bfloat162float(X[base + tid]);
  const float x1 = __bfloat162float(X[base + 256 + tid]);
  float s = x0 + x1, q = x0 * x0 + x1 * x1;
  for (int o = 32; o; o >>= 1) { s += __shfl_down(s, o); q += __shfl_down(q, o); }
  __shared__ float sm[8];
  const int w = tid >> 6, lane = tid & 63;
  if (!lane) { sm[w] = s; sm[4 + w] = q; }
  __syncthreads();
  const float S = sm[0] + sm[1] + sm[2] + sm[3];
  const float Q = sm[4] + sm[5] + sm[6] + sm[7];
  const float mu = S * (1.0f / 512.0f);
  const float rs = rsqrtf(Q * (1.0f / 512.0f) - mu * mu + 1e-5f);
  X[base + tid]       = __float2bfloat16(fmaxf((x0 - mu) * rs * g[tid] + b[tid], 0.0f));
  X[base + 256 + tid] = __float2bfloat16(fmaxf((x1 - mu) * rs * g[tid + 256] + b[tid + 256], 0.0f));
}

// per row: softmax over 2048 (full row), then * exp(-5*dist) * (!mask), in-place bf16
__global__ __launch_bounds__(256) void softmax_adj(
    bf16_t* __restrict__ SC, const float* __restrict__ coords,
    const int* __restrict__ mask)
{
  const int bs = blockIdx.x;            // b*2048 + s
  const int b = bs >> 11, s = bs & 2047;
  const long base = (long)bs * 2048;
  const int tid = threadIdx.x;
  float rv[8];
  float mx = -3.0e38f;
#pragma unroll
  for (int i = 0; i < 8; ++i) {
    rv[i] = __bfloat162float(SC[base + i * 256 + tid]);
    mx = fmaxf(mx, rv[i]);
  }
  for (int o = 32; o; o >>= 1) mx = fmaxf(mx, __shfl_down(mx, o));
  __shared__ float sm[8];
  const int w = tid >> 6, lane = tid & 63;
  if (!lane) sm[w] = mx;
  __syncthreads();
  mx = fmaxf(fmaxf(sm[0], sm[1]), fmaxf(sm[2], sm[3]));
  float sum = 0.0f;
#pragma unroll
  for (int i = 0; i < 8; ++i) { rv[i] = __expf(rv[i] - mx); sum += rv[i]; }
  for (int o = 32; o; o >>= 1) sum += __shfl_down(sum, o);
  if (!lane) sm[4 + w] = sum;
  __syncthreads();
  const float inv = 1.0f / (sm[4] + sm[5] + sm[6] + sm[7]);
  const float px = coords[((long)b * 2048 + s) * 3];
  const float py = coords[((long)b * 2048 + s) * 3 + 1];
  const float* cb = coords + (long)b * 2048 * 3;
  const int* mb = mask + b * 2048;
#pragma unroll
  for (int i = 0; i < 8; ++i) {
    const int t = i * 256 + tid;
    const float dx = px - cb[t * 3], dy = py - cb[t * 3 + 1];
    const float adj = __expf(-5.0f * sqrtf(dx * dx + dy * dy));
    const float val = mb[t] ? 0.0f : rv[i] * inv * adj;
    SC[base + t] = __float2bfloat16(val);
  }
}

// LayerNorm(256)+ReLU on f32 rows, masked accumulate into pooled_acc[b][256]
__global__ __launch_bounds__(256) void ln2_pool(
    const float* __restrict__ X, const float* __restrict__ g, const float* __restrict__ bt,
    const int* __restrict__ mask, float* __restrict__ pacc)
{
  const int tid = threadIdx.x;
  const int row0 = blockIdx.x * 16;
  const int w = tid >> 6, lane = tid & 63;
  __shared__ float sm[8];
  const float gv = g[tid], bv = bt[tid];
  float acc = 0.0f;
  for (int r = 0; r < 16; ++r) {
    const int row = row0 + r;
    const float x = X[(long)row * 256 + tid];
    float s = x, q = x * x;
    for (int o = 32; o; o >>= 1) { s += __shfl_down(s, o); q += __shfl_down(q, o); }
    if (!lane) { sm[w] = s; sm[4 + w] = q; }
    __syncthreads();
    const float S = sm[0] + sm[1] + sm[2] + sm[3];
    const float Q = sm[4] + sm[5] + sm[6] + sm[7];
    const float mu = S * (1.0f / 256.0f);
    const float rs = rsqrtf(Q * (1.0f / 256.0f) - mu * mu + 1e-5f);
    const float y = fmaxf((x - mu) * rs * gv + bv, 0.0f);
    if (!mask[row]) acc += y;
    __syncthreads();
  }
  atomicAdd(&pacc[(row0 >> 11) * 256 + tid], acc);
}

// counts, pooled=acc/count -> out[80..], relu(pooled@w1+b1)@w2+b2 -> out[0..80)
__global__ __launch_bounds__(256) void classifier_k(
    const float* __restrict__ pacc, const int* __restrict__ mask,
    const float* __restrict__ w1, const float* __restrict__ b1,
    const float* __restrict__ w2, const float* __restrict__ b2,
    float* __restrict__ out)
{
  const int tid = threadIdx.x;
  __shared__ float pooled[2048];
  __shared__ float hidden[1024];
  __shared__ float cnt[8];
  if (tid < 8) cnt[tid] = 0.0f;
  __syncthreads();
  {
    const int* mb = mask + tid * 64;
    int c = 0;
#pragma unroll 8
    for (int i = 0; i < 64; ++i) c += mb[i] ? 0 : 1;
    atomicAdd(&cnt[tid >> 5], (float)c);
  }
  __syncthreads();
  for (int i = tid; i < 2048; i += 256) {
    const float p = pacc[i] / fmaxf(cnt[i >> 8], 1e-9f);
    pooled[i] = p;
    out[80 + i] = p;
  }
  __syncthreads();
  for (int o = tid; o < 1024; o += 256) {
    const int bb = o >> 7, j = o & 127;
    float s = b1[j];
    const float* pb = pooled + bb * 256;
    for (int c = 0; c < 256; ++c) s += pb[c] * w1[c * 128 + j];
    hidden[o] = fmaxf(s, 0.0f);
  }
  __syncthreads();
  if (tid < 80) {
    const int bb = tid / 10, j = tid - bb * 10;
    float s = b2[j];
    const float* hb = hidden + bb * 128;
    for (int c = 0; c < 128; ++c) s += hb[c] * w2[c * 10 + j];
    out[tid] = s;
  }
}

extern "C" void kernel_launch(void* const* d_in, const int* in_sizes, int n_in,
                              void* d_out, int out_size, void* d_ws, size_t ws_size,
                              hipStream_t stream)
{
  const float* lf   = (const float*)d_in[0];
  const float* co   = (const float*)d_in[1];
  const int*   mk   = (const int*)d_in[2];
  const float* wenc = (const float*)d_in[3];
  const float* benc = (const float*)d_in[4];
  const float* g1   = (const float*)d_in[5];
  const float* be1  = (const float*)d_in[6];
  const float* wq   = (const float*)d_in[7];
  const float* bq   = (const float*)d_in[8];
  const float* wk   = (const float*)d_in[9];
  const float* bk   = (const float*)d_in[10];
  const float* wv   = (const float*)d_in[11];
  const float* bvp  = (const float*)d_in[12];
  const float* wbn  = (const float*)d_in[13];
  const float* bbn  = (const float*)d_in[14];
  const float* g2   = (const float*)d_in[15];
  const float* be2  = (const float*)d_in[16];
  const float* w1   = (const float*)d_in[17];
  const float* b1   = (const float*)d_in[18];
  const float* w2   = (const float*)d_in[19];
  const float* b2   = (const float*)d_in[20];
  float* out = (float*)d_out;
  char* ws = (char*)d_ws;

  bf16_t* featb = (bf16_t*)(ws + 0);
  bf16_t* wencT = (bf16_t*)(ws + 16777216);
  bf16_t* wqT   = (bf16_t*)(ws + 17301504);
  bf16_t* wkT   = (bf16_t*)(ws + 17825792);
  bf16_t* wvT   = (bf16_t*)(ws + 18350080);
  bf16_t* wbnT  = (bf16_t*)(ws + 18874368);
  bf16_t* h     = (bf16_t*)(ws + 19136512);
  bf16_t* q     = (bf16_t*)(ws + 35913728);
  bf16_t* k     = (bf16_t*)(ws + 52690944);
  bf16_t* vT    = (bf16_t*)(ws + 69468160);
  bf16_t* sc    = (bf16_t*)(ws + 86245376);
  bf16_t* hg    = (bf16_t*)(ws + 153354240);
  float*  bnp   = (float*)(ws + 170131456);
  float*  pacc  = (float*)(ws + 186908672);

  if (ws_size < 186916864) return;  // ws too small: fail visibly rather than fault

  cast_bf16_k<<<32768, 256, 0, stream>>>(lf, featb, 16384 * 512);
  transpose_cast_k<<<1024, 256, 0, stream>>>(wenc, wencT, 512, 512);
  transpose_cast_k<<<1024, 256, 0, stream>>>(wq, wqT, 512, 512);
  transpose_cast_k<<<1024, 256, 0, stream>>>(wk, wkT, 512, 512);
  transpose_cast_k<<<1024, 256, 0, stream>>>(wv, wvT, 512, 512);
  transpose_cast_k<<<512, 256, 0, stream>>>(wbn, wbnT, 512, 256);

  // h_pre = feat @ w_enc + b_enc
  gemm_bt<<<dim3(4, 128, 1), 256, 0, stream>>>(featb, wencT, h, benc, 1.0f, 512, 0, 0, 0, 512, 0);
  ln_relu_h<<<16384, 256, 0, stream>>>(h, g1, be1);
  gemm_bt<<<dim3(4, 128, 1), 256, 0, stream>>>(h, wqT, q, bq, 1.0f, 512, 0, 0, 0, 512, 0);
  gemm_bt<<<dim3(4, 128, 1), 256, 0, stream>>>(h, wkT, k, bk, 1.0f, 512, 0, 0, 0, 512, 0);
  gemm_bt<<<dim3(4, 128, 1), 256, 0, stream>>>(h, wvT, vT, bvp, 1.0f, 512, 0, 0, 0, 512, 1);
  // scores[b] = q_b k_b^T / sqrt(512)
  gemm_bt<<<dim3(16, 16, 8), 256, 0, stream>>>(q, k, sc, nullptr, 0.044194173824159216f, 512,
                                               1048576, 1048576, 4194304, 2048, 0);
  softmax_adj<<<16384, 256, 0, stream>>>(sc, co, mk);
  // hg[b] = attn_b @ v_b   (B = v^T, N=512, K=2048)
  gemm_bt<<<dim3(4, 16, 8), 256, 0, stream>>>(sc, vT, hg, nullptr, 1.0f, 2048,
                                              4194304, 1048576, 1048576, 512, 0);
  // bn_pre = hg @ w_bn + b_bn  (f32 out)
  gemm_bt<<<dim3(2, 128, 1), 256, 0, stream>>>(hg, wbnT, bnp, bbn, 1.0f, 512, 0, 0, 0, 256, 2);
  hipMemsetAsync(pacc, 0, 8192, stream);
  ln2_pool<<<1024, 256, 0, stream>>>(bnp, g2, be2, mk, pacc);
  classifier_k<<<1, 256, 0, stream>>>(pacc, mk, w1, b1, w2, b2, out);
}